// Round 7
// baseline (901.332 us; speedup 1.0000x reference)
//
#include <hip/hip_runtime.h>
#include <math.h>

#define N_NODES 50000
#define N_EDGES 800000
#define HID 128
#define OUTC 64
#define NLAYERS 8

#define SCAN_B 64
#define SCAN_T 256
#define SCAN_C 4   // 64*256*4 = 65536 >= 50000

// ---------------- bf16 helpers (manual, RNE) ----------------

__device__ __forceinline__ float bfloat_lo(unsigned int u) {
    return __int_as_float((int)(u << 16));
}
__device__ __forceinline__ float bfloat_hi(unsigned int u) {
    return __int_as_float((int)(u & 0xFFFF0000u));
}
__device__ __forceinline__ unsigned int f2bf(float f) {
    unsigned int u = (unsigned int)__float_as_int(f);
    return (u + 0x7FFFu + ((u >> 16) & 1u)) >> 16;
}
__device__ __forceinline__ unsigned int pack2bf(float a, float b) {
    return f2bf(a) | (f2bf(b) << 16);
}

// ---------------- CSR build ----------------

__global__ void k_zero(int* __restrict__ p, int n) {
    int i = blockIdx.x * blockDim.x + threadIdx.x;
    if (i < n) p[i] = 0;
}

__global__ void k_count(const int* __restrict__ dst, int* __restrict__ deg, int E) {
    int e = blockIdx.x * blockDim.x + threadIdx.x;
    if (e < E) atomicAdd(&deg[dst[e]], 1);
}

__global__ __launch_bounds__(SCAN_T) void k_scanA(const int* __restrict__ deg, int* __restrict__ bsum) {
    __shared__ int red[SCAN_T];
    const int t = threadIdx.x, b = blockIdx.x;
    const int g = b * SCAN_T + t;
    int lo = g * SCAN_C; if (lo > N_NODES) lo = N_NODES;
    int hi = lo + SCAN_C; if (hi > N_NODES) hi = N_NODES;
    int s = 0;
    for (int i = lo; i < hi; i++) s += deg[i];
    red[t] = s;
    __syncthreads();
    for (int d = SCAN_T / 2; d > 0; d >>= 1) {
        if (t < d) red[t] += red[t + d];
        __syncthreads();
    }
    if (t == 0) bsum[b] = red[0];
}

__global__ __launch_bounds__(SCAN_T) void k_scanB(int* __restrict__ cur, int* __restrict__ off,
                                                  const int* __restrict__ bsum) {
    __shared__ int pre[SCAN_T];
    __shared__ int baseSh;
    const int t = threadIdx.x, b = blockIdx.x;
    const int g = b * SCAN_T + t;
    int lo = g * SCAN_C; if (lo > N_NODES) lo = N_NODES;
    int hi = lo + SCAN_C; if (hi > N_NODES) hi = N_NODES;
    int s = 0;
    for (int i = lo; i < hi; i++) s += cur[i];
    pre[t] = s;
    if (t == 0) {
        int acc = 0;
        for (int j = 0; j < b; j++) acc += bsum[j];
        baseSh = acc;
    }
    __syncthreads();
    for (int d = 1; d < SCAN_T; d <<= 1) {
        int v = (t >= d) ? pre[t - d] : 0;
        __syncthreads();
        pre[t] += v;
        __syncthreads();
    }
    int running = baseSh + pre[t] - s;
    for (int i = lo; i < hi; i++) {
        int d = cur[i];
        off[i] = running;
        cur[i] = running;
        running += d;
        if (i == N_NODES - 1) off[N_NODES] = running;
    }
}

__global__ void k_scatter(const int* __restrict__ src, const int* __restrict__ dst,
                          const float* __restrict__ w, int* __restrict__ cursor,
                          int2* __restrict__ ep, int E) {
    int e = blockIdx.x * blockDim.x + threadIdx.x;
    if (e < E) {
        int d = dst[e];
        int pos = atomicAdd(&cursor[d], 1);
        ep[pos] = make_int2(src[e], __float_as_int(w[e]));
    }
}

// ---------------- paired-edge bf16 gather (128 ch) ----------------
// lanes 0-31 process even-slot edges, 32-63 odd-slot; each lane loads 4 ch (uint2).
// acc[i] is channel sub*4+i, partial (one half's edges); caller shfl_xor(32)-reduces.
__device__ __forceinline__ void gatherPair128(const int2* __restrict__ ep, int lo, int hi,
                                              const uint2* __restrict__ featsU2,
                                              int sub, int half, float acc[4])
{
    const int lane = threadIdx.x & 63;
    for (int base = lo; base < hi; base += 64) {
        const int cnt = min(hi - base, 64);
        int2 ev = make_int2(0, 0);                 // pad lanes: w = 0 (safe)
        if (lane < cnt) ev = ep[base + lane];
        const int kmax = (cnt + 1) & ~1;
        int j = 0;
        for (; j + 8 <= kmax; j += 8) {            // 4 pairs = 8 edges in flight
            int e0 = j + half, e1 = j + 2 + half, e2 = j + 4 + half, e3 = j + 6 + half;
            int s0 = __shfl(ev.x, e0), s1 = __shfl(ev.x, e1);
            int s2 = __shfl(ev.x, e2), s3 = __shfl(ev.x, e3);
            float w0 = __int_as_float(__shfl(ev.y, e0));
            float w1 = __int_as_float(__shfl(ev.y, e1));
            float w2 = __int_as_float(__shfl(ev.y, e2));
            float w3 = __int_as_float(__shfl(ev.y, e3));
            uint2 u0 = featsU2[(size_t)s0 * 32 + sub];
            uint2 u1 = featsU2[(size_t)s1 * 32 + sub];
            uint2 u2 = featsU2[(size_t)s2 * 32 + sub];
            uint2 u3 = featsU2[(size_t)s3 * 32 + sub];
            acc[0] = fmaf(w0, bfloat_lo(u0.x), acc[0]);
            acc[1] = fmaf(w0, bfloat_hi(u0.x), acc[1]);
            acc[2] = fmaf(w0, bfloat_lo(u0.y), acc[2]);
            acc[3] = fmaf(w0, bfloat_hi(u0.y), acc[3]);
            acc[0] = fmaf(w1, bfloat_lo(u1.x), acc[0]);
            acc[1] = fmaf(w1, bfloat_hi(u1.x), acc[1]);
            acc[2] = fmaf(w1, bfloat_lo(u1.y), acc[2]);
            acc[3] = fmaf(w1, bfloat_hi(u1.y), acc[3]);
            acc[0] = fmaf(w2, bfloat_lo(u2.x), acc[0]);
            acc[1] = fmaf(w2, bfloat_hi(u2.x), acc[1]);
            acc[2] = fmaf(w2, bfloat_lo(u2.y), acc[2]);
            acc[3] = fmaf(w2, bfloat_hi(u2.y), acc[3]);
            acc[0] = fmaf(w3, bfloat_lo(u3.x), acc[0]);
            acc[1] = fmaf(w3, bfloat_hi(u3.x), acc[1]);
            acc[2] = fmaf(w3, bfloat_lo(u3.y), acc[2]);
            acc[3] = fmaf(w3, bfloat_hi(u3.y), acc[3]);
        }
        for (; j < kmax; j += 2) {
            int e = j + half;
            int s = __shfl(ev.x, e);
            float w = __int_as_float(__shfl(ev.y, e));
            uint2 u = featsU2[(size_t)s * 32 + sub];
            acc[0] = fmaf(w, bfloat_lo(u.x), acc[0]);
            acc[1] = fmaf(w, bfloat_hi(u.x), acc[1]);
            acc[2] = fmaf(w, bfloat_lo(u.y), acc[2]);
            acc[3] = fmaf(w, bfloat_hi(u.y), acc[3]);
        }
    }
}

// ---------------- input spmm: h0 = relu(spmm(z bf16) + b_in) -> h bf16 AND x0 fp32 ----------------
__global__ __launch_bounds__(256) void k_spmm_in(
    const int* __restrict__ off, const int2* __restrict__ ep,
    const uint2* __restrict__ zU2, const float* __restrict__ b_in,
    uint2* __restrict__ hU2, float* __restrict__ x0)
{
    const int wave = threadIdx.x >> 6;
    const int lane = threadIdx.x & 63;
    const int node = blockIdx.x * 4 + wave;
    if (node >= N_NODES) return;
    const int sub = lane & 31, half = lane >> 5;

    float acc[4] = {0.f, 0.f, 0.f, 0.f};
    gatherPair128(ep, off[node], off[node + 1], zU2, sub, half, acc);
    #pragma unroll
    for (int i = 0; i < 4; i++) acc[i] += __shfl_xor(acc[i], 32);

    if (half == 0) {
        const int c = sub * 4;
        float4 r;
        r.x = fmaxf(acc[0] + b_in[c + 0], 0.f);
        r.y = fmaxf(acc[1] + b_in[c + 1], 0.f);
        r.z = fmaxf(acc[2] + b_in[c + 2], 0.f);
        r.w = fmaxf(acc[3] + b_in[c + 3], 0.f);
        *(float4*)(x0 + (size_t)node * 128 + c) = r;
        hU2[(size_t)node * 32 + sub] = make_uint2(pack2bf(r.x, r.y), pack2bf(r.z, r.w));
    }
}

// ---------------- final spmm: out = spmm(y bf16, 64ch) + b_out (4 edges per load) ----------------
__global__ __launch_bounds__(256) void k_spmm_out(
    const int* __restrict__ off, const int2* __restrict__ ep,
    const uint2* __restrict__ yU2, const float* __restrict__ b_out,
    float* __restrict__ out)
{
    const int wave = threadIdx.x >> 6;
    const int lane = threadIdx.x & 63;
    const int node = blockIdx.x * 4 + wave;
    if (node >= N_NODES) return;
    const int q = lane >> 4;       // edge slot within quad
    const int s16 = lane & 15;     // ch group: ch = s16*4..+3

    float acc[4] = {0.f, 0.f, 0.f, 0.f};
    const int lo = off[node], hi = off[node + 1];
    for (int base = lo; base < hi; base += 64) {
        const int cnt = min(hi - base, 64);
        int2 ev = make_int2(0, 0);
        if (lane < cnt) ev = ep[base + lane];
        const int kmax = (cnt + 3) & ~3;
        int j = 0;
        for (; j + 8 <= kmax; j += 8) {            // 2 quads = 8 edges
            int e0 = j + q, e1 = j + 4 + q;
            int s0 = __shfl(ev.x, e0), s1 = __shfl(ev.x, e1);
            float w0 = __int_as_float(__shfl(ev.y, e0));
            float w1 = __int_as_float(__shfl(ev.y, e1));
            uint2 u0 = yU2[(size_t)s0 * 16 + s16];
            uint2 u1 = yU2[(size_t)s1 * 16 + s16];
            acc[0] = fmaf(w0, bfloat_lo(u0.x), acc[0]);
            acc[1] = fmaf(w0, bfloat_hi(u0.x), acc[1]);
            acc[2] = fmaf(w0, bfloat_lo(u0.y), acc[2]);
            acc[3] = fmaf(w0, bfloat_hi(u0.y), acc[3]);
            acc[0] = fmaf(w1, bfloat_lo(u1.x), acc[0]);
            acc[1] = fmaf(w1, bfloat_hi(u1.x), acc[1]);
            acc[2] = fmaf(w1, bfloat_lo(u1.y), acc[2]);
            acc[3] = fmaf(w1, bfloat_hi(u1.y), acc[3]);
        }
        for (; j < kmax; j += 4) {
            int e = j + q;
            int s = __shfl(ev.x, e);
            float w = __int_as_float(__shfl(ev.y, e));
            uint2 u = yU2[(size_t)s * 16 + s16];
            acc[0] = fmaf(w, bfloat_lo(u.x), acc[0]);
            acc[1] = fmaf(w, bfloat_hi(u.x), acc[1]);
            acc[2] = fmaf(w, bfloat_lo(u.y), acc[2]);
            acc[3] = fmaf(w, bfloat_hi(u.y), acc[3]);
        }
    }
    #pragma unroll
    for (int i = 0; i < 4; i++) {
        acc[i] += __shfl_xor(acc[i], 16);
        acc[i] += __shfl_xor(acc[i], 32);
    }
    if (lane < 16) {
        const int c = s16 * 4;
        float4 o;
        o.x = acc[0] + b_out[c + 0];
        o.y = acc[1] + b_out[c + 1];
        o.z = acc[2] + b_out[c + 2];
        o.w = acc[3] + b_out[c + 3];
        *(float4*)(out + (size_t)node * 64 + c) = o;
    }
}

// ---------------- input GEMM: z(bf16) = x @ W_in ----------------
__global__ __launch_bounds__(256) void k_gemm_in(
    const float* __restrict__ A, const float* __restrict__ W,
    uint2* __restrict__ zU2)
{
    __shared__ float As[32][128];
    const int tid = threadIdx.x;
    const int row0 = blockIdx.x * 32;
    {
        const float4* srcp = (const float4*)(A + (size_t)row0 * 128);
        float4* dl = (float4*)(&As[0][0]);
        #pragma unroll
        for (int it = 0; it < 4; it++) {
            int idx = tid + it * 256;
            int r = idx >> 5;
            float4 v = make_float4(0.f, 0.f, 0.f, 0.f);
            if (row0 + r < N_NODES) v = srcp[idx];
            dl[idx] = v;
        }
    }
    __syncthreads();

    const int rg = tid >> 5;
    const int c0 = (tid & 31) * 4;
    float acc[4][4];
    #pragma unroll
    for (int i = 0; i < 4; i++)
        #pragma unroll
        for (int j = 0; j < 4; j++) acc[i][j] = 0.f;

    #pragma unroll 4
    for (int k = 0; k < 128; k++) {
        float a0 = As[rg * 4 + 0][k], a1 = As[rg * 4 + 1][k];
        float a2 = As[rg * 4 + 2][k], a3 = As[rg * 4 + 3][k];
        float4 wv = *(const float4*)(W + (size_t)k * 128 + c0);
        float w[4] = {wv.x, wv.y, wv.z, wv.w};
        #pragma unroll
        for (int j = 0; j < 4; j++) {
            acc[0][j] = fmaf(a0, w[j], acc[0][j]);
            acc[1][j] = fmaf(a1, w[j], acc[1][j]);
            acc[2][j] = fmaf(a2, w[j], acc[2][j]);
            acc[3][j] = fmaf(a3, w[j], acc[3][j]);
        }
    }

    #pragma unroll
    for (int i = 0; i < 4; i++) {
        int r = row0 + rg * 4 + i;
        if (r < N_NODES) {
            zU2[(size_t)r * 32 + (c0 >> 2)] =
                make_uint2(pack2bf(acc[i][0], acc[i][1]), pack2bf(acc[i][2], acc[i][3]));
        }
    }
}

// ---------------- fused layer (16-row tile, 3125 blocks) ----------------
// h_out(bf16) = relu((1-beta)*t + beta*(t @ W)),  t = 0.5*spmm(h bf16) + 0.5*x0(fp32)
__global__ __launch_bounds__(256) void k_layer(
    const int* __restrict__ off, const int2* __restrict__ ep,
    const uint2* __restrict__ hU2, const float* __restrict__ x0,
    const float* __restrict__ W, uint2* __restrict__ hOutU2, float beta)
{
    __shared__ float As[16][128];
    const int tid = threadIdx.x;
    const int wave = tid >> 6, lane = tid & 63;
    const int sub = lane & 31, half = lane >> 5;
    const int row0 = blockIdx.x * 16;

    // phase 1: spmm -> t -> LDS (each wave: 4 nodes)
    #pragma unroll 1
    for (int i = 0; i < 4; i++) {
        const int r = wave * 4 + i;
        const int node = row0 + r;
        float acc[4] = {0.f, 0.f, 0.f, 0.f};
        if (node < N_NODES)
            gatherPair128(ep, off[node], off[node + 1], hU2, sub, half, acc);
        #pragma unroll
        for (int qq = 0; qq < 4; qq++) acc[qq] += __shfl_xor(acc[qq], 32);
        if (half == 0) {
            const int c = sub * 4;
            float4 x0v = make_float4(0.f, 0.f, 0.f, 0.f);
            if (node < N_NODES) x0v = *(const float4*)(x0 + (size_t)node * 128 + c);
            float4 t;
            t.x = 0.5f * acc[0] + 0.5f * x0v.x;
            t.y = 0.5f * acc[1] + 0.5f * x0v.y;
            t.z = 0.5f * acc[2] + 0.5f * x0v.z;
            t.w = 0.5f * acc[3] + 0.5f * x0v.w;
            *(float4*)(&As[r][c]) = t;
        }
    }
    __syncthreads();

    // phase 2: gemm (16x128 tile) + GCNII epilogue, h' written bf16
    const int rg = tid >> 5;          // rows rg*2, rg*2+1
    const int c0 = (tid & 31) * 4;

    float acc2[2][4];
    #pragma unroll
    for (int i = 0; i < 2; i++)
        #pragma unroll
        for (int j = 0; j < 4; j++) acc2[i][j] = 0.f;

    #pragma unroll 4
    for (int k = 0; k < 128; k++) {
        float a0 = As[rg * 2 + 0][k];
        float a1 = As[rg * 2 + 1][k];
        float4 wv = *(const float4*)(W + (size_t)k * 128 + c0);
        float w[4] = {wv.x, wv.y, wv.z, wv.w};
        #pragma unroll
        for (int j = 0; j < 4; j++) {
            acc2[0][j] = fmaf(a0, w[j], acc2[0][j]);
            acc2[1][j] = fmaf(a1, w[j], acc2[1][j]);
        }
    }

    const float omb = 1.f - beta;
    #pragma unroll
    for (int i = 0; i < 2; i++) {
        int r = row0 + rg * 2 + i;
        if (r < N_NODES) {
            float v0 = fmaxf(omb * As[rg * 2 + i][c0 + 0] + beta * acc2[i][0], 0.f);
            float v1 = fmaxf(omb * As[rg * 2 + i][c0 + 1] + beta * acc2[i][1], 0.f);
            float v2 = fmaxf(omb * As[rg * 2 + i][c0 + 2] + beta * acc2[i][2], 0.f);
            float v3 = fmaxf(omb * As[rg * 2 + i][c0 + 3] + beta * acc2[i][3], 0.f);
            hOutU2[(size_t)r * 32 + (c0 >> 2)] =
                make_uint2(pack2bf(v0, v1), pack2bf(v2, v3));
        }
    }
}

// ---------------- output GEMM: y(bf16) = h(bf16) @ W_out ----------------
__global__ __launch_bounds__(256) void k_gemm_out(
    const uint2* __restrict__ hU2, const float* __restrict__ W,
    uint2* __restrict__ yU2)
{
    __shared__ float As[32][128];
    const int tid = threadIdx.x;
    const int row0 = blockIdx.x * 32;
    {
        const uint4* srcp = (const uint4*)hU2;   // row = 16 uint4 (8 ch each)
        #pragma unroll
        for (int it = 0; it < 2; it++) {
            int idx = tid + it * 256;           // 0..511
            int r = idx >> 4;
            int cc = (idx & 15) * 8;
            uint4 v = make_uint4(0u, 0u, 0u, 0u);
            if (row0 + r < N_NODES) v = srcp[(size_t)(row0 + r) * 16 + (idx & 15)];
            As[r][cc + 0] = bfloat_lo(v.x); As[r][cc + 1] = bfloat_hi(v.x);
            As[r][cc + 2] = bfloat_lo(v.y); As[r][cc + 3] = bfloat_hi(v.y);
            As[r][cc + 4] = bfloat_lo(v.z); As[r][cc + 5] = bfloat_hi(v.z);
            As[r][cc + 6] = bfloat_lo(v.w); As[r][cc + 7] = bfloat_hi(v.w);
        }
    }
    __syncthreads();

    const int rg = tid >> 5;
    const int c0 = (tid & 31) * 2;
    float acc[4][2];
    #pragma unroll
    for (int i = 0; i < 4; i++) { acc[i][0] = 0.f; acc[i][1] = 0.f; }

    #pragma unroll 4
    for (int k = 0; k < 128; k++) {
        float a0 = As[rg * 4 + 0][k], a1 = As[rg * 4 + 1][k];
        float a2 = As[rg * 4 + 2][k], a3 = As[rg * 4 + 3][k];
        float2 wv = *(const float2*)(W + (size_t)k * OUTC + c0);
        acc[0][0] = fmaf(a0, wv.x, acc[0][0]); acc[0][1] = fmaf(a0, wv.y, acc[0][1]);
        acc[1][0] = fmaf(a1, wv.x, acc[1][0]); acc[1][1] = fmaf(a1, wv.y, acc[1][1]);
        acc[2][0] = fmaf(a2, wv.x, acc[2][0]); acc[2][1] = fmaf(a2, wv.y, acc[2][1]);
        acc[3][0] = fmaf(a3, wv.x, acc[3][0]); acc[3][1] = fmaf(a3, wv.y, acc[3][1]);
    }

    unsigned int* yU = (unsigned int*)yU2;
    #pragma unroll
    for (int i = 0; i < 4; i++) {
        int r = row0 + rg * 4 + i;
        if (r < N_NODES) {
            yU[(size_t)r * 32 + (c0 >> 1)] = pack2bf(acc[i][0], acc[i][1]);
        }
    }
}

// ---------------- launch ----------------

extern "C" void kernel_launch(void* const* d_in, const int* in_sizes, int n_in,
                              void* d_out, int out_size, void* d_ws, size_t ws_size,
                              hipStream_t stream)
{
    const float* x     = (const float*)d_in[0];
    const int*   ei    = (const int*)d_in[1];
    const float* ew    = (const float*)d_in[2];
    const float* W_in  = (const float*)d_in[3];
    const float* b_in  = (const float*)d_in[4];
    const float* W_lay = (const float*)d_in[5];
    const float* W_out = (const float*)d_in[6];
    const float* b_out = (const float*)d_in[7];
    float* out = (float*)d_out;

    const int* src = ei;
    const int* dst = ei + N_EDGES;

    char* p = (char*)d_ws;
    auto alloc = [&](size_t bytes) -> char* {
        char* q = p;
        p += (bytes + 255) & ~(size_t)255;
        return q;
    };
    int*   cursor = (int*)alloc((size_t)N_NODES * 4);
    int*   off    = (int*)alloc((size_t)(N_NODES + 1) * 4);
    int2*  ep     = (int2*)alloc((size_t)N_EDGES * 8);
    int*   bsum   = (int*)alloc((size_t)SCAN_B * 4);
    uint2* zU2    = (uint2*)alloc((size_t)N_NODES * 32 * 8);   // z bf16 [N][128]
    float* bufX0  = (float*)alloc((size_t)N_NODES * HID * 4);  // x0 fp32
    uint2* hA     = (uint2*)alloc((size_t)N_NODES * 32 * 8);   // h bf16 [N][128]
    uint2* hB     = (uint2*)alloc((size_t)N_NODES * 32 * 8);
    uint2* yB     = (uint2*)alloc((size_t)N_NODES * 16 * 8);   // y bf16 [N][64]

    // CSR build
    k_zero<<<(N_NODES + 255) / 256, 256, 0, stream>>>(cursor, N_NODES);
    k_count<<<(N_EDGES + 255) / 256, 256, 0, stream>>>(dst, cursor, N_EDGES);
    k_scanA<<<SCAN_B, SCAN_T, 0, stream>>>(cursor, bsum);
    k_scanB<<<SCAN_B, SCAN_T, 0, stream>>>(cursor, off, bsum);
    k_scatter<<<(N_EDGES + 255) / 256, 256, 0, stream>>>(src, dst, ew, cursor, ep, N_EDGES);

    const int gemmGrid  = (N_NODES + 31) / 32;   // 1563
    const int layerGrid = (N_NODES + 15) / 16;   // 3125
    const int spmmGrid  = (N_NODES + 3) / 4;     // 12500

    // z = x @ W_in -> zU2 (bf16)
    k_gemm_in<<<gemmGrid, 256, 0, stream>>>(x, W_in, zU2);
    // h0 = relu(spmm(z) + b_in) -> hA (bf16), x0 (fp32)
    k_spmm_in<<<spmmGrid, 256, 0, stream>>>(off, ep, zU2, b_in, hA, bufX0);

    uint2* hin = hA;
    uint2* hout = hB;
    for (int l = 0; l < NLAYERS; l++) {
        float beta = logf(1.0f / (float)(l + 1) + 1.0f);
        k_layer<<<layerGrid, 256, 0, stream>>>(off, ep, hin, bufX0,
                                               W_lay + (size_t)l * HID * HID, hout, beta);
        uint2* tmp = hin; hin = hout; hout = tmp;
    }

    // y = h @ W_out -> yB (bf16)
    k_gemm_out<<<gemmGrid, 256, 0, stream>>>(hin, W_out, yB);
    // out = spmm(y) + b_out
    k_spmm_out<<<spmmGrid, 256, 0, stream>>>(off, ep, yB, b_out, out);
}

// Round 8
// 890.627 us; speedup vs baseline: 1.0120x; 1.0120x over previous
//
#include <hip/hip_runtime.h>
#include <math.h>

#define N_NODES 50000
#define N_EDGES 800000
#define HID 128
#define OUTC 64
#define NLAYERS 8

#define SCAN_B 64
#define SCAN_T 256
#define SCAN_C 4   // 64*256*4 = 65536 >= 50000

// ---------------- bf16 helpers (manual, RNE) ----------------

__device__ __forceinline__ float bfloat_lo(unsigned int u) {
    return __int_as_float((int)(u << 16));
}
__device__ __forceinline__ float bfloat_hi(unsigned int u) {
    return __int_as_float((int)(u & 0xFFFF0000u));
}
__device__ __forceinline__ unsigned int f2bf(float f) {
    unsigned int u = (unsigned int)__float_as_int(f);
    return (u + 0x7FFFu + ((u >> 16) & 1u)) >> 16;
}
__device__ __forceinline__ unsigned int pack2bf(float a, float b) {
    return f2bf(a) | (f2bf(b) << 16);
}

// ---------------- CSR build ----------------

__global__ void k_zero(int* __restrict__ p, int n) {
    int i = blockIdx.x * blockDim.x + threadIdx.x;
    if (i < n) p[i] = 0;
}

__global__ void k_count(const int* __restrict__ dst, int* __restrict__ deg, int E) {
    int e = blockIdx.x * blockDim.x + threadIdx.x;
    if (e < E) atomicAdd(&deg[dst[e]], 1);
}

__global__ __launch_bounds__(SCAN_T) void k_scanA(const int* __restrict__ deg, int* __restrict__ bsum) {
    __shared__ int red[SCAN_T];
    const int t = threadIdx.x, b = blockIdx.x;
    const int g = b * SCAN_T + t;
    int lo = g * SCAN_C; if (lo > N_NODES) lo = N_NODES;
    int hi = lo + SCAN_C; if (hi > N_NODES) hi = N_NODES;
    int s = 0;
    for (int i = lo; i < hi; i++) s += deg[i];
    red[t] = s;
    __syncthreads();
    for (int d = SCAN_T / 2; d > 0; d >>= 1) {
        if (t < d) red[t] += red[t + d];
        __syncthreads();
    }
    if (t == 0) bsum[b] = red[0];
}

__global__ __launch_bounds__(SCAN_T) void k_scanB(int* __restrict__ cur, int* __restrict__ off,
                                                  const int* __restrict__ bsum) {
    __shared__ int pre[SCAN_T];
    __shared__ int baseSh;
    const int t = threadIdx.x, b = blockIdx.x;
    const int g = b * SCAN_T + t;
    int lo = g * SCAN_C; if (lo > N_NODES) lo = N_NODES;
    int hi = lo + SCAN_C; if (hi > N_NODES) hi = N_NODES;
    int s = 0;
    for (int i = lo; i < hi; i++) s += cur[i];
    pre[t] = s;
    if (t == 0) {
        int acc = 0;
        for (int j = 0; j < b; j++) acc += bsum[j];
        baseSh = acc;
    }
    __syncthreads();
    for (int d = 1; d < SCAN_T; d <<= 1) {
        int v = (t >= d) ? pre[t - d] : 0;
        __syncthreads();
        pre[t] += v;
        __syncthreads();
    }
    int running = baseSh + pre[t] - s;
    for (int i = lo; i < hi; i++) {
        int d = cur[i];
        off[i] = running;
        cur[i] = running;
        running += d;
        if (i == N_NODES - 1) off[N_NODES] = running;
    }
}

__global__ void k_scatter(const int* __restrict__ src, const int* __restrict__ dst,
                          const float* __restrict__ w, int* __restrict__ cursor,
                          int2* __restrict__ ep, int E) {
    int e = blockIdx.x * blockDim.x + threadIdx.x;
    if (e < E) {
        int d = dst[e];
        int pos = atomicAdd(&cursor[d], 1);
        ep[pos] = make_int2(src[e], __float_as_int(w[e]));
    }
}

// ---------------- bf16 gather (128 ch): one edge per wave-instruction ----------------
// lane covers ch c=lane*2 -> one u32 load per edge (row = 64 u32, fully coalesced 256B)
// 8 independent row loads in flight per unroll step.
__device__ __forceinline__ void gatherB2(const int2* __restrict__ ep, int lo, int hi,
                                         const unsigned int* __restrict__ featsU, int lane,
                                         float& ax, float& ay)
{
    for (int base = lo; base < hi; base += 64) {
        const int cnt = min(hi - base, 64);
        int2 ev = make_int2(0, 0);
        if (lane < cnt) ev = ep[base + lane];
        int j = 0;
        for (; j + 8 <= cnt; j += 8) {
            int s0 = __shfl(ev.x, j + 0), s1 = __shfl(ev.x, j + 1);
            int s2 = __shfl(ev.x, j + 2), s3 = __shfl(ev.x, j + 3);
            int s4 = __shfl(ev.x, j + 4), s5 = __shfl(ev.x, j + 5);
            int s6 = __shfl(ev.x, j + 6), s7 = __shfl(ev.x, j + 7);
            float w0 = __int_as_float(__shfl(ev.y, j + 0));
            float w1 = __int_as_float(__shfl(ev.y, j + 1));
            float w2 = __int_as_float(__shfl(ev.y, j + 2));
            float w3 = __int_as_float(__shfl(ev.y, j + 3));
            float w4 = __int_as_float(__shfl(ev.y, j + 4));
            float w5 = __int_as_float(__shfl(ev.y, j + 5));
            float w6 = __int_as_float(__shfl(ev.y, j + 6));
            float w7 = __int_as_float(__shfl(ev.y, j + 7));
            unsigned int u0 = featsU[(size_t)s0 * 64 + lane];
            unsigned int u1 = featsU[(size_t)s1 * 64 + lane];
            unsigned int u2 = featsU[(size_t)s2 * 64 + lane];
            unsigned int u3 = featsU[(size_t)s3 * 64 + lane];
            unsigned int u4 = featsU[(size_t)s4 * 64 + lane];
            unsigned int u5 = featsU[(size_t)s5 * 64 + lane];
            unsigned int u6 = featsU[(size_t)s6 * 64 + lane];
            unsigned int u7 = featsU[(size_t)s7 * 64 + lane];
            ax = fmaf(w0, bfloat_lo(u0), ax); ay = fmaf(w0, bfloat_hi(u0), ay);
            ax = fmaf(w1, bfloat_lo(u1), ax); ay = fmaf(w1, bfloat_hi(u1), ay);
            ax = fmaf(w2, bfloat_lo(u2), ax); ay = fmaf(w2, bfloat_hi(u2), ay);
            ax = fmaf(w3, bfloat_lo(u3), ax); ay = fmaf(w3, bfloat_hi(u3), ay);
            ax = fmaf(w4, bfloat_lo(u4), ax); ay = fmaf(w4, bfloat_hi(u4), ay);
            ax = fmaf(w5, bfloat_lo(u5), ax); ay = fmaf(w5, bfloat_hi(u5), ay);
            ax = fmaf(w6, bfloat_lo(u6), ax); ay = fmaf(w6, bfloat_hi(u6), ay);
            ax = fmaf(w7, bfloat_lo(u7), ax); ay = fmaf(w7, bfloat_hi(u7), ay);
        }
        for (; j < cnt; j++) {
            int s = __shfl(ev.x, j);
            float w = __int_as_float(__shfl(ev.y, j));
            unsigned int u = featsU[(size_t)s * 64 + lane];
            ax = fmaf(w, bfloat_lo(u), ax); ay = fmaf(w, bfloat_hi(u), ay);
        }
    }
}

// ---------------- input spmm: h0 = relu(spmm(z bf16) + b_in) -> h bf16 AND x0 bf16 ----------------
__global__ __launch_bounds__(256) void k_spmm_in(
    const int* __restrict__ off, const int2* __restrict__ ep,
    const unsigned int* __restrict__ zU, const float* __restrict__ b_in,
    unsigned int* __restrict__ hU, unsigned int* __restrict__ x0U)
{
    const int wave = threadIdx.x >> 6;
    const int lane = threadIdx.x & 63;
    const int node = blockIdx.x * 4 + wave;
    if (node >= N_NODES) return;
    const int lo = off[node], hi = off[node + 1];

    float ax = 0.f, ay = 0.f;
    gatherB2(ep, lo, hi, zU, lane, ax, ay);
    const int c = lane * 2;
    float r0 = fmaxf(ax + b_in[c], 0.f);
    float r1 = fmaxf(ay + b_in[c + 1], 0.f);
    unsigned int pk = pack2bf(r0, r1);
    hU [(size_t)node * 64 + lane] = pk;
    x0U[(size_t)node * 64 + lane] = pk;
}

// ---------------- final spmm: out = spmm(y bf16, 64ch) + b_out (4 edges per load) ----------------
__global__ __launch_bounds__(256) void k_spmm_out(
    const int* __restrict__ off, const int2* __restrict__ ep,
    const uint2* __restrict__ yU2, const float* __restrict__ b_out,
    float* __restrict__ out)
{
    const int wave = threadIdx.x >> 6;
    const int lane = threadIdx.x & 63;
    const int node = blockIdx.x * 4 + wave;
    if (node >= N_NODES) return;
    const int q = lane >> 4;       // edge slot within quad
    const int s16 = lane & 15;     // ch group: ch = s16*4..+3

    float acc[4] = {0.f, 0.f, 0.f, 0.f};
    const int lo = off[node], hi = off[node + 1];
    for (int base = lo; base < hi; base += 64) {
        const int cnt = min(hi - base, 64);
        int2 ev = make_int2(0, 0);
        if (lane < cnt) ev = ep[base + lane];
        const int kmax = (cnt + 3) & ~3;
        int j = 0;
        for (; j + 8 <= kmax; j += 8) {
            int e0 = j + q, e1 = j + 4 + q;
            int s0 = __shfl(ev.x, e0), s1 = __shfl(ev.x, e1);
            float w0 = __int_as_float(__shfl(ev.y, e0));
            float w1 = __int_as_float(__shfl(ev.y, e1));
            uint2 u0 = yU2[(size_t)s0 * 16 + s16];
            uint2 u1 = yU2[(size_t)s1 * 16 + s16];
            acc[0] = fmaf(w0, bfloat_lo(u0.x), acc[0]);
            acc[1] = fmaf(w0, bfloat_hi(u0.x), acc[1]);
            acc[2] = fmaf(w0, bfloat_lo(u0.y), acc[2]);
            acc[3] = fmaf(w0, bfloat_hi(u0.y), acc[3]);
            acc[0] = fmaf(w1, bfloat_lo(u1.x), acc[0]);
            acc[1] = fmaf(w1, bfloat_hi(u1.x), acc[1]);
            acc[2] = fmaf(w1, bfloat_lo(u1.y), acc[2]);
            acc[3] = fmaf(w1, bfloat_hi(u1.y), acc[3]);
        }
        for (; j < kmax; j += 4) {
            int e = j + q;
            int s = __shfl(ev.x, e);
            float w = __int_as_float(__shfl(ev.y, e));
            uint2 u = yU2[(size_t)s * 16 + s16];
            acc[0] = fmaf(w, bfloat_lo(u.x), acc[0]);
            acc[1] = fmaf(w, bfloat_hi(u.x), acc[1]);
            acc[2] = fmaf(w, bfloat_lo(u.y), acc[2]);
            acc[3] = fmaf(w, bfloat_hi(u.y), acc[3]);
        }
    }
    #pragma unroll
    for (int i = 0; i < 4; i++) {
        acc[i] += __shfl_xor(acc[i], 16);
        acc[i] += __shfl_xor(acc[i], 32);
    }
    if (lane < 16) {
        const int c = s16 * 4;
        float4 o;
        o.x = acc[0] + b_out[c + 0];
        o.y = acc[1] + b_out[c + 1];
        o.z = acc[2] + b_out[c + 2];
        o.w = acc[3] + b_out[c + 3];
        *(float4*)(out + (size_t)node * 64 + c) = o;
    }
}

// ---------------- input GEMM: z(bf16) = x @ W_in ----------------
__global__ __launch_bounds__(256) void k_gemm_in(
    const float* __restrict__ A, const float* __restrict__ W,
    unsigned int* __restrict__ zU)
{
    __shared__ float As[32][128];
    const int tid = threadIdx.x;
    const int row0 = blockIdx.x * 32;
    {
        const float4* srcp = (const float4*)(A + (size_t)row0 * 128);
        float4* dl = (float4*)(&As[0][0]);
        #pragma unroll
        for (int it = 0; it < 4; it++) {
            int idx = tid + it * 256;
            int r = idx >> 5;
            float4 v = make_float4(0.f, 0.f, 0.f, 0.f);
            if (row0 + r < N_NODES) v = srcp[idx];
            dl[idx] = v;
        }
    }
    __syncthreads();

    const int rg = tid >> 5;
    const int c0 = (tid & 31) * 4;
    float acc[4][4];
    #pragma unroll
    for (int i = 0; i < 4; i++)
        #pragma unroll
        for (int j = 0; j < 4; j++) acc[i][j] = 0.f;

    #pragma unroll 4
    for (int k = 0; k < 128; k++) {
        float a0 = As[rg * 4 + 0][k], a1 = As[rg * 4 + 1][k];
        float a2 = As[rg * 4 + 2][k], a3 = As[rg * 4 + 3][k];
        float4 wv = *(const float4*)(W + (size_t)k * 128 + c0);
        float w[4] = {wv.x, wv.y, wv.z, wv.w};
        #pragma unroll
        for (int j = 0; j < 4; j++) {
            acc[0][j] = fmaf(a0, w[j], acc[0][j]);
            acc[1][j] = fmaf(a1, w[j], acc[1][j]);
            acc[2][j] = fmaf(a2, w[j], acc[2][j]);
            acc[3][j] = fmaf(a3, w[j], acc[3][j]);
        }
    }

    #pragma unroll
    for (int i = 0; i < 4; i++) {
        int r = row0 + rg * 4 + i;
        if (r < N_NODES) {
            uint2 pk = make_uint2(pack2bf(acc[i][0], acc[i][1]), pack2bf(acc[i][2], acc[i][3]));
            *(uint2*)(zU + (size_t)r * 64 + (c0 >> 1)) = pk;
        }
    }
}

// ---------------- fused layer (16-row tile, 3125 blocks, tail-free) ----------------
// h_out(bf16) = relu((1-beta)*t + beta*(t @ W)),  t = 0.5*spmm(h bf16) + 0.5*x0(bf16)
__global__ __launch_bounds__(256) void k_layer(
    const int* __restrict__ off, const int2* __restrict__ ep,
    const unsigned int* __restrict__ hU, const unsigned int* __restrict__ x0U,
    const float* __restrict__ W, unsigned int* __restrict__ hOutU, float beta)
{
    __shared__ float As[16][128];
    const int tid = threadIdx.x;
    const int wave = tid >> 6, lane = tid & 63;
    const int row0 = blockIdx.x * 16;       // 50000 = 3125*16: no tail, all nodes valid
    const int wnode0 = row0 + wave * 4;
    const int c = lane * 2;

    // preload off[wnode0 .. wnode0+4] wave-parallel (removes 8 serial scalar loads)
    int offv = 0;
    if (lane < 5) offv = off[wnode0 + lane];

    // phase 1: spmm -> t -> LDS (each wave: 4 nodes)
    #pragma unroll 1
    for (int i = 0; i < 4; i++) {
        const int node = wnode0 + i;
        const int lo = __shfl(offv, i), hi = __shfl(offv, i + 1);
        float ax = 0.f, ay = 0.f;
        gatherB2(ep, lo, hi, hU, lane, ax, ay);
        unsigned int xv = x0U[(size_t)node * 64 + lane];
        ax = 0.5f * ax + 0.5f * bfloat_lo(xv);
        ay = 0.5f * ay + 0.5f * bfloat_hi(xv);
        *(float2*)(&As[wave * 4 + i][c]) = make_float2(ax, ay);
    }
    __syncthreads();

    // phase 2: gemm (16x128 tile) + GCNII epilogue, h' written bf16
    const int rg = tid >> 5;          // rows rg*2, rg*2+1
    const int c0 = (tid & 31) * 4;

    float acc2[2][4];
    #pragma unroll
    for (int i = 0; i < 2; i++)
        #pragma unroll
        for (int j = 0; j < 4; j++) acc2[i][j] = 0.f;

    #pragma unroll 4
    for (int k = 0; k < 128; k++) {
        float a0 = As[rg * 2 + 0][k];
        float a1 = As[rg * 2 + 1][k];
        float4 wv = *(const float4*)(W + (size_t)k * 128 + c0);
        float w[4] = {wv.x, wv.y, wv.z, wv.w};
        #pragma unroll
        for (int j = 0; j < 4; j++) {
            acc2[0][j] = fmaf(a0, w[j], acc2[0][j]);
            acc2[1][j] = fmaf(a1, w[j], acc2[1][j]);
        }
    }

    const float omb = 1.f - beta;
    #pragma unroll
    for (int i = 0; i < 2; i++) {
        int r = row0 + rg * 2 + i;
        float v0 = fmaxf(omb * As[rg * 2 + i][c0 + 0] + beta * acc2[i][0], 0.f);
        float v1 = fmaxf(omb * As[rg * 2 + i][c0 + 1] + beta * acc2[i][1], 0.f);
        float v2 = fmaxf(omb * As[rg * 2 + i][c0 + 2] + beta * acc2[i][2], 0.f);
        float v3 = fmaxf(omb * As[rg * 2 + i][c0 + 3] + beta * acc2[i][3], 0.f);
        uint2 pk = make_uint2(pack2bf(v0, v1), pack2bf(v2, v3));
        *(uint2*)(hOutU + (size_t)r * 64 + (c0 >> 1)) = pk;
    }
}

// ---------------- output GEMM: y(bf16) = h(bf16) @ W_out ----------------
__global__ __launch_bounds__(256) void k_gemm_out(
    const unsigned int* __restrict__ hU, const float* __restrict__ W,
    unsigned int* __restrict__ yU)
{
    __shared__ float As[32][128];
    const int tid = threadIdx.x;
    const int row0 = blockIdx.x * 32;
    {
        const uint4* srcp = (const uint4*)hU;   // row = 16 uint4 (8 ch each)
        #pragma unroll
        for (int it = 0; it < 2; it++) {
            int idx = tid + it * 256;           // 0..511
            int r = idx >> 4;
            int cc = (idx & 15) * 8;
            uint4 v = make_uint4(0u, 0u, 0u, 0u);
            if (row0 + r < N_NODES) v = srcp[(size_t)(row0 + r) * 16 + (idx & 15)];
            As[r][cc + 0] = bfloat_lo(v.x); As[r][cc + 1] = bfloat_hi(v.x);
            As[r][cc + 2] = bfloat_lo(v.y); As[r][cc + 3] = bfloat_hi(v.y);
            As[r][cc + 4] = bfloat_lo(v.z); As[r][cc + 5] = bfloat_hi(v.z);
            As[r][cc + 6] = bfloat_lo(v.w); As[r][cc + 7] = bfloat_hi(v.w);
        }
    }
    __syncthreads();

    const int rg = tid >> 5;
    const int c0 = (tid & 31) * 2;
    float acc[4][2];
    #pragma unroll
    for (int i = 0; i < 4; i++) { acc[i][0] = 0.f; acc[i][1] = 0.f; }

    #pragma unroll 4
    for (int k = 0; k < 128; k++) {
        float a0 = As[rg * 4 + 0][k], a1 = As[rg * 4 + 1][k];
        float a2 = As[rg * 4 + 2][k], a3 = As[rg * 4 + 3][k];
        float2 wv = *(const float2*)(W + (size_t)k * OUTC + c0);
        acc[0][0] = fmaf(a0, wv.x, acc[0][0]); acc[0][1] = fmaf(a0, wv.y, acc[0][1]);
        acc[1][0] = fmaf(a1, wv.x, acc[1][0]); acc[1][1] = fmaf(a1, wv.y, acc[1][1]);
        acc[2][0] = fmaf(a2, wv.x, acc[2][0]); acc[2][1] = fmaf(a2, wv.y, acc[2][1]);
        acc[3][0] = fmaf(a3, wv.x, acc[3][0]); acc[3][1] = fmaf(a3, wv.y, acc[3][1]);
    }

    #pragma unroll
    for (int i = 0; i < 4; i++) {
        int r = row0 + rg * 4 + i;
        if (r < N_NODES) {
            yU[(size_t)r * 32 + (c0 >> 1)] = pack2bf(acc[i][0], acc[i][1]);
        }
    }
}

// ---------------- launch ----------------

extern "C" void kernel_launch(void* const* d_in, const int* in_sizes, int n_in,
                              void* d_out, int out_size, void* d_ws, size_t ws_size,
                              hipStream_t stream)
{
    const float* x     = (const float*)d_in[0];
    const int*   ei    = (const int*)d_in[1];
    const float* ew    = (const float*)d_in[2];
    const float* W_in  = (const float*)d_in[3];
    const float* b_in  = (const float*)d_in[4];
    const float* W_lay = (const float*)d_in[5];
    const float* W_out = (const float*)d_in[6];
    const float* b_out = (const float*)d_in[7];
    float* out = (float*)d_out;

    const int* src = ei;
    const int* dst = ei + N_EDGES;

    char* p = (char*)d_ws;
    auto alloc = [&](size_t bytes) -> char* {
        char* q = p;
        p += (bytes + 255) & ~(size_t)255;
        return q;
    };
    int*          cursor = (int*)alloc((size_t)N_NODES * 4);
    int*          off    = (int*)alloc((size_t)(N_NODES + 1) * 4);
    int2*         ep     = (int2*)alloc((size_t)N_EDGES * 8);
    int*          bsum   = (int*)alloc((size_t)SCAN_B * 4);
    unsigned int* zU     = (unsigned int*)alloc((size_t)N_NODES * 64 * 4); // z bf16 [N][128]
    unsigned int* x0U    = (unsigned int*)alloc((size_t)N_NODES * 64 * 4); // x0 bf16
    unsigned int* hA     = (unsigned int*)alloc((size_t)N_NODES * 64 * 4); // h bf16
    unsigned int* hB     = (unsigned int*)alloc((size_t)N_NODES * 64 * 4);
    unsigned int* yB     = (unsigned int*)alloc((size_t)N_NODES * 32 * 4); // y bf16 [N][64]

    // CSR build
    k_zero<<<(N_NODES + 255) / 256, 256, 0, stream>>>(cursor, N_NODES);
    k_count<<<(N_EDGES + 255) / 256, 256, 0, stream>>>(dst, cursor, N_EDGES);
    k_scanA<<<SCAN_B, SCAN_T, 0, stream>>>(cursor, bsum);
    k_scanB<<<SCAN_B, SCAN_T, 0, stream>>>(cursor, off, bsum);
    k_scatter<<<(N_EDGES + 255) / 256, 256, 0, stream>>>(src, dst, ew, cursor, ep, N_EDGES);

    const int gemmGrid  = (N_NODES + 31) / 32;   // 1563
    const int layerGrid = (N_NODES + 15) / 16;   // 3125 (exact)
    const int spmmGrid  = (N_NODES + 3) / 4;     // 12500 (exact)

    // z = x @ W_in -> zU (bf16)
    k_gemm_in<<<gemmGrid, 256, 0, stream>>>(x, W_in, zU);
    // h0 = relu(spmm(z) + b_in) -> hA (bf16), x0U (bf16)
    k_spmm_in<<<spmmGrid, 256, 0, stream>>>(off, ep, zU, b_in, hA, x0U);

    unsigned int* hin = hA;
    unsigned int* hout = hB;
    for (int l = 0; l < NLAYERS; l++) {
        float beta = logf(1.0f / (float)(l + 1) + 1.0f);
        k_layer<<<layerGrid, 256, 0, stream>>>(off, ep, hin, x0U,
                                               W_lay + (size_t)l * HID * HID, hout, beta);
        unsigned int* tmp = hin; hin = hout; hout = tmp;
    }

    // y = h @ W_out -> yB (bf16)
    k_gemm_out<<<gemmGrid, 256, 0, stream>>>(hin, W_out, yB);
    // out = spmm(y) + b_out
    k_spmm_out<<<spmmGrid, 256, 0, stream>>>(off, ep, (const uint2*)yB, b_out, out);
}

// Round 9
// 748.416 us; speedup vs baseline: 1.2043x; 1.1900x over previous
//
#include <hip/hip_runtime.h>
#include <math.h>

#define N_NODES 50000
#define N_EDGES 800000
#define HID 128
#define OUTC 64
#define NLAYERS 8

#define SCAN_B 64
#define SCAN_T 256
#define SCAN_C 4   // 64*256*4 = 65536 >= 50000

// ---------------- bf16 helpers (manual, RNE) ----------------

__device__ __forceinline__ float bfloat_lo(unsigned int u) {
    return __int_as_float((int)(u << 16));
}
__device__ __forceinline__ float bfloat_hi(unsigned int u) {
    return __int_as_float((int)(u & 0xFFFF0000u));
}
__device__ __forceinline__ unsigned int f2bf(float f) {
    unsigned int u = (unsigned int)__float_as_int(f);
    return (u + 0x7FFFu + ((u >> 16) & 1u)) >> 16;
}
__device__ __forceinline__ unsigned int pack2bf(float a, float b) {
    return f2bf(a) | (f2bf(b) << 16);
}

// ---------------- CSR build ----------------

__global__ void k_zero(int* __restrict__ p, int n) {
    int i = blockIdx.x * blockDim.x + threadIdx.x;
    if (i < n) p[i] = 0;
}

__global__ void k_count(const int* __restrict__ dst, int* __restrict__ deg, int E) {
    int e = blockIdx.x * blockDim.x + threadIdx.x;
    if (e < E) atomicAdd(&deg[dst[e]], 1);
}

__global__ __launch_bounds__(SCAN_T) void k_scanA(const int* __restrict__ deg, int* __restrict__ bsum) {
    __shared__ int red[SCAN_T];
    const int t = threadIdx.x, b = blockIdx.x;
    const int g = b * SCAN_T + t;
    int lo = g * SCAN_C; if (lo > N_NODES) lo = N_NODES;
    int hi = lo + SCAN_C; if (hi > N_NODES) hi = N_NODES;
    int s = 0;
    for (int i = lo; i < hi; i++) s += deg[i];
    red[t] = s;
    __syncthreads();
    for (int d = SCAN_T / 2; d > 0; d >>= 1) {
        if (t < d) red[t] += red[t + d];
        __syncthreads();
    }
    if (t == 0) bsum[b] = red[0];
}

__global__ __launch_bounds__(SCAN_T) void k_scanB(int* __restrict__ cur, int* __restrict__ off,
                                                  const int* __restrict__ bsum) {
    __shared__ int pre[SCAN_T];
    __shared__ int baseSh;
    const int t = threadIdx.x, b = blockIdx.x;
    const int g = b * SCAN_T + t;
    int lo = g * SCAN_C; if (lo > N_NODES) lo = N_NODES;
    int hi = lo + SCAN_C; if (hi > N_NODES) hi = N_NODES;
    int s = 0;
    for (int i = lo; i < hi; i++) s += cur[i];
    pre[t] = s;
    if (t == 0) {
        int acc = 0;
        for (int j = 0; j < b; j++) acc += bsum[j];
        baseSh = acc;
    }
    __syncthreads();
    for (int d = 1; d < SCAN_T; d <<= 1) {
        int v = (t >= d) ? pre[t - d] : 0;
        __syncthreads();
        pre[t] += v;
        __syncthreads();
    }
    int running = baseSh + pre[t] - s;
    for (int i = lo; i < hi; i++) {
        int d = cur[i];
        off[i] = running;
        cur[i] = running;
        running += d;
        if (i == N_NODES - 1) off[N_NODES] = running;
    }
}

__global__ void k_scatter(const int* __restrict__ src, const int* __restrict__ dst,
                          const float* __restrict__ w, int* __restrict__ cursor,
                          int2* __restrict__ ep, int E) {
    int e = blockIdx.x * blockDim.x + threadIdx.x;
    if (e < E) {
        int d = dst[e];
        int pos = atomicAdd(&cursor[d], 1);
        ep[pos] = make_int2(src[e], __float_as_int(w[e]));
    }
}

// ---------------- bf16 gather (128 ch): one edge per wave-instruction ----------------
// lane covers ch c=lane*2 -> one u32 load per edge (row = 64 u32, fully coalesced 256B)
// 8 independent row loads in flight per unroll step.
__device__ __forceinline__ void gatherB2(const int2* __restrict__ ep, int lo, int hi,
                                         const unsigned int* __restrict__ featsU, int lane,
                                         float& ax, float& ay)
{
    for (int base = lo; base < hi; base += 64) {
        const int cnt = min(hi - base, 64);
        int2 ev = make_int2(0, 0);
        if (lane < cnt) ev = ep[base + lane];
        int j = 0;
        for (; j + 8 <= cnt; j += 8) {
            int s0 = __shfl(ev.x, j + 0), s1 = __shfl(ev.x, j + 1);
            int s2 = __shfl(ev.x, j + 2), s3 = __shfl(ev.x, j + 3);
            int s4 = __shfl(ev.x, j + 4), s5 = __shfl(ev.x, j + 5);
            int s6 = __shfl(ev.x, j + 6), s7 = __shfl(ev.x, j + 7);
            float w0 = __int_as_float(__shfl(ev.y, j + 0));
            float w1 = __int_as_float(__shfl(ev.y, j + 1));
            float w2 = __int_as_float(__shfl(ev.y, j + 2));
            float w3 = __int_as_float(__shfl(ev.y, j + 3));
            float w4 = __int_as_float(__shfl(ev.y, j + 4));
            float w5 = __int_as_float(__shfl(ev.y, j + 5));
            float w6 = __int_as_float(__shfl(ev.y, j + 6));
            float w7 = __int_as_float(__shfl(ev.y, j + 7));
            unsigned int u0 = featsU[(size_t)s0 * 64 + lane];
            unsigned int u1 = featsU[(size_t)s1 * 64 + lane];
            unsigned int u2 = featsU[(size_t)s2 * 64 + lane];
            unsigned int u3 = featsU[(size_t)s3 * 64 + lane];
            unsigned int u4 = featsU[(size_t)s4 * 64 + lane];
            unsigned int u5 = featsU[(size_t)s5 * 64 + lane];
            unsigned int u6 = featsU[(size_t)s6 * 64 + lane];
            unsigned int u7 = featsU[(size_t)s7 * 64 + lane];
            ax = fmaf(w0, bfloat_lo(u0), ax); ay = fmaf(w0, bfloat_hi(u0), ay);
            ax = fmaf(w1, bfloat_lo(u1), ax); ay = fmaf(w1, bfloat_hi(u1), ay);
            ax = fmaf(w2, bfloat_lo(u2), ax); ay = fmaf(w2, bfloat_hi(u2), ay);
            ax = fmaf(w3, bfloat_lo(u3), ax); ay = fmaf(w3, bfloat_hi(u3), ay);
            ax = fmaf(w4, bfloat_lo(u4), ax); ay = fmaf(w4, bfloat_hi(u4), ay);
            ax = fmaf(w5, bfloat_lo(u5), ax); ay = fmaf(w5, bfloat_hi(u5), ay);
            ax = fmaf(w6, bfloat_lo(u6), ax); ay = fmaf(w6, bfloat_hi(u6), ay);
            ax = fmaf(w7, bfloat_lo(u7), ax); ay = fmaf(w7, bfloat_hi(u7), ay);
        }
        for (; j < cnt; j++) {
            int s = __shfl(ev.x, j);
            float w = __int_as_float(__shfl(ev.y, j));
            unsigned int u = featsU[(size_t)s * 64 + lane];
            ax = fmaf(w, bfloat_lo(u), ax); ay = fmaf(w, bfloat_hi(u), ay);
        }
    }
}

// ---------------- input spmm: h0 = relu(spmm(z bf16) + b_in) -> h bf16 AND x0 bf16 ----------------
__global__ __launch_bounds__(256) void k_spmm_in(
    const int* __restrict__ off, const int2* __restrict__ ep,
    const unsigned int* __restrict__ zU, const float* __restrict__ b_in,
    unsigned int* __restrict__ hU, unsigned int* __restrict__ x0U)
{
    const int wave = threadIdx.x >> 6;
    const int lane = threadIdx.x & 63;
    const int node = blockIdx.x * 4 + wave;
    if (node >= N_NODES) return;
    const int lo = off[node], hi = off[node + 1];

    float ax = 0.f, ay = 0.f;
    gatherB2(ep, lo, hi, zU, lane, ax, ay);
    const int c = lane * 2;
    float r0 = fmaxf(ax + b_in[c], 0.f);
    float r1 = fmaxf(ay + b_in[c + 1], 0.f);
    unsigned int pk = pack2bf(r0, r1);
    hU [(size_t)node * 64 + lane] = pk;
    x0U[(size_t)node * 64 + lane] = pk;
}

// ---------------- final spmm: out = spmm(y bf16, 64ch) + b_out (4 edges per load) ----------------
__global__ __launch_bounds__(256) void k_spmm_out(
    const int* __restrict__ off, const int2* __restrict__ ep,
    const uint2* __restrict__ yU2, const float* __restrict__ b_out,
    float* __restrict__ out)
{
    const int wave = threadIdx.x >> 6;
    const int lane = threadIdx.x & 63;
    const int node = blockIdx.x * 4 + wave;
    if (node >= N_NODES) return;
    const int q = lane >> 4;       // edge slot within quad
    const int s16 = lane & 15;     // ch group: ch = s16*4..+3

    float acc[4] = {0.f, 0.f, 0.f, 0.f};
    const int lo = off[node], hi = off[node + 1];
    for (int base = lo; base < hi; base += 64) {
        const int cnt = min(hi - base, 64);
        int2 ev = make_int2(0, 0);
        if (lane < cnt) ev = ep[base + lane];
        const int kmax = (cnt + 3) & ~3;
        int j = 0;
        for (; j + 8 <= kmax; j += 8) {
            int e0 = j + q, e1 = j + 4 + q;
            int s0 = __shfl(ev.x, e0), s1 = __shfl(ev.x, e1);
            float w0 = __int_as_float(__shfl(ev.y, e0));
            float w1 = __int_as_float(__shfl(ev.y, e1));
            uint2 u0 = yU2[(size_t)s0 * 16 + s16];
            uint2 u1 = yU2[(size_t)s1 * 16 + s16];
            acc[0] = fmaf(w0, bfloat_lo(u0.x), acc[0]);
            acc[1] = fmaf(w0, bfloat_hi(u0.x), acc[1]);
            acc[2] = fmaf(w0, bfloat_lo(u0.y), acc[2]);
            acc[3] = fmaf(w0, bfloat_hi(u0.y), acc[3]);
            acc[0] = fmaf(w1, bfloat_lo(u1.x), acc[0]);
            acc[1] = fmaf(w1, bfloat_hi(u1.x), acc[1]);
            acc[2] = fmaf(w1, bfloat_lo(u1.y), acc[2]);
            acc[3] = fmaf(w1, bfloat_hi(u1.y), acc[3]);
        }
        for (; j < kmax; j += 4) {
            int e = j + q;
            int s = __shfl(ev.x, e);
            float w = __int_as_float(__shfl(ev.y, e));
            uint2 u = yU2[(size_t)s * 16 + s16];
            acc[0] = fmaf(w, bfloat_lo(u.x), acc[0]);
            acc[1] = fmaf(w, bfloat_hi(u.x), acc[1]);
            acc[2] = fmaf(w, bfloat_lo(u.y), acc[2]);
            acc[3] = fmaf(w, bfloat_hi(u.y), acc[3]);
        }
    }
    #pragma unroll
    for (int i = 0; i < 4; i++) {
        acc[i] += __shfl_xor(acc[i], 16);
        acc[i] += __shfl_xor(acc[i], 32);
    }
    if (lane < 16) {
        const int c = s16 * 4;
        float4 o;
        o.x = acc[0] + b_out[c + 0];
        o.y = acc[1] + b_out[c + 1];
        o.z = acc[2] + b_out[c + 2];
        o.w = acc[3] + b_out[c + 3];
        *(float4*)(out + (size_t)node * 64 + c) = o;
    }
}

// ---------------- input GEMM: z(bf16) = x @ W_in ----------------
__global__ __launch_bounds__(256) void k_gemm_in(
    const float* __restrict__ A, const float* __restrict__ W,
    unsigned int* __restrict__ zU)
{
    __shared__ float As[32][128];
    const int tid = threadIdx.x;
    const int row0 = blockIdx.x * 32;
    {
        const float4* srcp = (const float4*)(A + (size_t)row0 * 128);
        float4* dl = (float4*)(&As[0][0]);
        #pragma unroll
        for (int it = 0; it < 4; it++) {
            int idx = tid + it * 256;
            int r = idx >> 5;
            float4 v = make_float4(0.f, 0.f, 0.f, 0.f);
            if (row0 + r < N_NODES) v = srcp[idx];
            dl[idx] = v;
        }
    }
    __syncthreads();

    const int rg = tid >> 5;
    const int c0 = (tid & 31) * 4;
    float acc[4][4];
    #pragma unroll
    for (int i = 0; i < 4; i++)
        #pragma unroll
        for (int j = 0; j < 4; j++) acc[i][j] = 0.f;

    #pragma unroll 4
    for (int k = 0; k < 128; k++) {
        float a0 = As[rg * 4 + 0][k], a1 = As[rg * 4 + 1][k];
        float a2 = As[rg * 4 + 2][k], a3 = As[rg * 4 + 3][k];
        float4 wv = *(const float4*)(W + (size_t)k * 128 + c0);
        float w[4] = {wv.x, wv.y, wv.z, wv.w};
        #pragma unroll
        for (int j = 0; j < 4; j++) {
            acc[0][j] = fmaf(a0, w[j], acc[0][j]);
            acc[1][j] = fmaf(a1, w[j], acc[1][j]);
            acc[2][j] = fmaf(a2, w[j], acc[2][j]);
            acc[3][j] = fmaf(a3, w[j], acc[3][j]);
        }
    }

    #pragma unroll
    for (int i = 0; i < 4; i++) {
        int r = row0 + rg * 4 + i;
        if (r < N_NODES) {
            uint2 pk = make_uint2(pack2bf(acc[i][0], acc[i][1]), pack2bf(acc[i][2], acc[i][3]));
            *(uint2*)(zU + (size_t)r * 64 + (c0 >> 1)) = pk;
        }
    }
}

// ---------------- fused layer (32-row tile, 1563 blocks — R6 structure) ----------------
// h_out(bf16) = relu((1-beta)*t + beta*(t @ W)),  t = 0.5*spmm(h bf16) + 0.5*x0(bf16)
__global__ __launch_bounds__(256) void k_layer(
    const int* __restrict__ off, const int2* __restrict__ ep,
    const unsigned int* __restrict__ hU, const unsigned int* __restrict__ x0U,
    const float* __restrict__ W, unsigned int* __restrict__ hOutU, float beta)
{
    __shared__ float As[32][128];
    const int tid = threadIdx.x;
    const int wave = tid >> 6, lane = tid & 63;
    const int row0 = blockIdx.x * 32;
    const int wnode0 = row0 + wave * 8;
    const int c = lane * 2;

    // preload off[wnode0 .. wnode0+8] wave-parallel (removes 16 serial scalar loads)
    int offv = 0;
    if (lane < 9) {
        int nn = wnode0 + lane;
        if (nn > N_NODES) nn = N_NODES;
        offv = off[nn];
    }

    // phase 1: spmm -> t -> LDS (each wave: 8 nodes)
    #pragma unroll 1
    for (int i = 0; i < 8; i++) {
        const int node = wnode0 + i;
        float ax = 0.f, ay = 0.f;
        if (node < N_NODES) {
            const int lo = __shfl(offv, i), hi = __shfl(offv, i + 1);
            gatherB2(ep, lo, hi, hU, lane, ax, ay);
            unsigned int xv = x0U[(size_t)node * 64 + lane];
            ax = 0.5f * ax + 0.5f * bfloat_lo(xv);
            ay = 0.5f * ay + 0.5f * bfloat_hi(xv);
        }
        *(float2*)(&As[wave * 8 + i][c]) = make_float2(ax, ay);
    }
    __syncthreads();

    // phase 2: gemm (32x128 tile) + GCNII epilogue, h' written bf16
    const int rg = tid >> 5;          // rows rg*4 .. rg*4+3
    const int c0 = (tid & 31) * 4;

    float acc[4][4];
    #pragma unroll
    for (int i = 0; i < 4; i++)
        #pragma unroll
        for (int j = 0; j < 4; j++) acc[i][j] = 0.f;

    #pragma unroll 4
    for (int k = 0; k < 128; k++) {
        float a0 = As[rg * 4 + 0][k], a1 = As[rg * 4 + 1][k];
        float a2 = As[rg * 4 + 2][k], a3 = As[rg * 4 + 3][k];
        float4 wv = *(const float4*)(W + (size_t)k * 128 + c0);
        float w[4] = {wv.x, wv.y, wv.z, wv.w};
        #pragma unroll
        for (int j = 0; j < 4; j++) {
            acc[0][j] = fmaf(a0, w[j], acc[0][j]);
            acc[1][j] = fmaf(a1, w[j], acc[1][j]);
            acc[2][j] = fmaf(a2, w[j], acc[2][j]);
            acc[3][j] = fmaf(a3, w[j], acc[3][j]);
        }
    }

    const float omb = 1.f - beta;
    #pragma unroll
    for (int i = 0; i < 4; i++) {
        int r = row0 + rg * 4 + i;
        if (r < N_NODES) {
            float v0 = fmaxf(omb * As[rg * 4 + i][c0 + 0] + beta * acc[i][0], 0.f);
            float v1 = fmaxf(omb * As[rg * 4 + i][c0 + 1] + beta * acc[i][1], 0.f);
            float v2 = fmaxf(omb * As[rg * 4 + i][c0 + 2] + beta * acc[i][2], 0.f);
            float v3 = fmaxf(omb * As[rg * 4 + i][c0 + 3] + beta * acc[i][3], 0.f);
            uint2 pk = make_uint2(pack2bf(v0, v1), pack2bf(v2, v3));
            *(uint2*)(hOutU + (size_t)r * 64 + (c0 >> 1)) = pk;
        }
    }
}

// ---------------- output GEMM: y(bf16) = h(bf16) @ W_out ----------------
__global__ __launch_bounds__(256) void k_gemm_out(
    const unsigned int* __restrict__ hU, const float* __restrict__ W,
    unsigned int* __restrict__ yU)
{
    __shared__ float As[32][128];
    const int tid = threadIdx.x;
    const int row0 = blockIdx.x * 32;
    {
        const uint4* srcp = (const uint4*)hU;   // row = 16 uint4 (8 ch each)
        #pragma unroll
        for (int it = 0; it < 2; it++) {
            int idx = tid + it * 256;           // 0..511
            int r = idx >> 4;
            int cc = (idx & 15) * 8;
            uint4 v = make_uint4(0u, 0u, 0u, 0u);
            if (row0 + r < N_NODES) v = srcp[(size_t)(row0 + r) * 16 + (idx & 15)];
            As[r][cc + 0] = bfloat_lo(v.x); As[r][cc + 1] = bfloat_hi(v.x);
            As[r][cc + 2] = bfloat_lo(v.y); As[r][cc + 3] = bfloat_hi(v.y);
            As[r][cc + 4] = bfloat_lo(v.z); As[r][cc + 5] = bfloat_hi(v.z);
            As[r][cc + 6] = bfloat_lo(v.w); As[r][cc + 7] = bfloat_hi(v.w);
        }
    }
    __syncthreads();

    const int rg = tid >> 5;
    const int c0 = (tid & 31) * 2;
    float acc[4][2];
    #pragma unroll
    for (int i = 0; i < 4; i++) { acc[i][0] = 0.f; acc[i][1] = 0.f; }

    #pragma unroll 4
    for (int k = 0; k < 128; k++) {
        float a0 = As[rg * 4 + 0][k], a1 = As[rg * 4 + 1][k];
        float a2 = As[rg * 4 + 2][k], a3 = As[rg * 4 + 3][k];
        float2 wv = *(const float2*)(W + (size_t)k * OUTC + c0);
        acc[0][0] = fmaf(a0, wv.x, acc[0][0]); acc[0][1] = fmaf(a0, wv.y, acc[0][1]);
        acc[1][0] = fmaf(a1, wv.x, acc[1][0]); acc[1][1] = fmaf(a1, wv.y, acc[1][1]);
        acc[2][0] = fmaf(a2, wv.x, acc[2][0]); acc[2][1] = fmaf(a2, wv.y, acc[2][1]);
        acc[3][0] = fmaf(a3, wv.x, acc[3][0]); acc[3][1] = fmaf(a3, wv.y, acc[3][1]);
    }

    #pragma unroll
    for (int i = 0; i < 4; i++) {
        int r = row0 + rg * 4 + i;
        if (r < N_NODES) {
            yU[(size_t)r * 32 + (c0 >> 1)] = pack2bf(acc[i][0], acc[i][1]);
        }
    }
}

// ---------------- launch ----------------

extern "C" void kernel_launch(void* const* d_in, const int* in_sizes, int n_in,
                              void* d_out, int out_size, void* d_ws, size_t ws_size,
                              hipStream_t stream)
{
    const float* x     = (const float*)d_in[0];
    const int*   ei    = (const int*)d_in[1];
    const float* ew    = (const float*)d_in[2];
    const float* W_in  = (const float*)d_in[3];
    const float* b_in  = (const float*)d_in[4];
    const float* W_lay = (const float*)d_in[5];
    const float* W_out = (const float*)d_in[6];
    const float* b_out = (const float*)d_in[7];
    float* out = (float*)d_out;

    const int* src = ei;
    const int* dst = ei + N_EDGES;

    char* p = (char*)d_ws;
    auto alloc = [&](size_t bytes) -> char* {
        char* q = p;
        p += (bytes + 255) & ~(size_t)255;
        return q;
    };
    int*          cursor = (int*)alloc((size_t)N_NODES * 4);
    int*          off    = (int*)alloc((size_t)(N_NODES + 1) * 4);
    int2*         ep     = (int2*)alloc((size_t)N_EDGES * 8);
    int*          bsum   = (int*)alloc((size_t)SCAN_B * 4);
    unsigned int* zU     = (unsigned int*)alloc((size_t)N_NODES * 64 * 4); // z bf16 [N][128]
    unsigned int* x0U    = (unsigned int*)alloc((size_t)N_NODES * 64 * 4); // x0 bf16
    unsigned int* hA     = (unsigned int*)alloc((size_t)N_NODES * 64 * 4); // h bf16
    unsigned int* hB     = (unsigned int*)alloc((size_t)N_NODES * 64 * 4);
    unsigned int* yB     = (unsigned int*)alloc((size_t)N_NODES * 32 * 4); // y bf16 [N][64]

    // CSR build
    k_zero<<<(N_NODES + 255) / 256, 256, 0, stream>>>(cursor, N_NODES);
    k_count<<<(N_EDGES + 255) / 256, 256, 0, stream>>>(dst, cursor, N_EDGES);
    k_scanA<<<SCAN_B, SCAN_T, 0, stream>>>(cursor, bsum);
    k_scanB<<<SCAN_B, SCAN_T, 0, stream>>>(cursor, off, bsum);
    k_scatter<<<(N_EDGES + 255) / 256, 256, 0, stream>>>(src, dst, ew, cursor, ep, N_EDGES);

    const int gemmGrid  = (N_NODES + 31) / 32;   // 1563
    const int spmmGrid  = (N_NODES + 3) / 4;     // 12500 (exact)

    // z = x @ W_in -> zU (bf16)
    k_gemm_in<<<gemmGrid, 256, 0, stream>>>(x, W_in, zU);
    // h0 = relu(spmm(z) + b_in) -> hA (bf16), x0U (bf16)
    k_spmm_in<<<spmmGrid, 256, 0, stream>>>(off, ep, zU, b_in, hA, x0U);

    unsigned int* hin = hA;
    unsigned int* hout = hB;
    for (int l = 0; l < NLAYERS; l++) {
        float beta = logf(1.0f / (float)(l + 1) + 1.0f);
        k_layer<<<gemmGrid, 256, 0, stream>>>(off, ep, hin, x0U,
                                              W_lay + (size_t)l * HID * HID, hout, beta);
        unsigned int* tmp = hin; hin = hout; hout = tmp;
    }

    // y = h @ W_out -> yB (bf16)
    k_gemm_out<<<gemmGrid, 256, 0, stream>>>(hin, W_out, yB);
    // out = spmm(y) + b_out
    k_spmm_out<<<spmmGrid, 256, 0, stream>>>(off, ep, (const uint2*)yB, b_out, out);
}